// Round 3
// baseline (700.968 us; speedup 1.0000x reference)
//
#include <hip/hip_runtime.h>

#define NN 50000
#define EE 800000
#define ET 850000   // EE + NN self loops
#define HH 4
#define CC 64
#define FDIM 256    // HH*CC

#define SCAN_BLK 512
#define SCAN_NB ((NN + SCAN_BLK - 1) / SCAN_BLK)   // 98

typedef unsigned short ushort;
typedef __bf16 bf16x8 __attribute__((ext_vector_type(8)));
typedef float floatx4 __attribute__((ext_vector_type(4)));
typedef ushort ushort8v __attribute__((ext_vector_type(8)));
typedef ushort ushort4v __attribute__((ext_vector_type(4)));
struct ushort4s { ushort x, y, z, w; };

__device__ __forceinline__ ushort f2bf(float f) {
  union { float f; unsigned u; } v; v.f = f;
  unsigned r = v.u + 0x7fffu + ((v.u >> 16) & 1u);  // RNE
  return (ushort)(r >> 16);
}
__device__ __forceinline__ float bf2f(ushort u) {
  return __uint_as_float(((unsigned)u) << 16);
}

// ---------- edge-index dtype handling (is64 decided HOST-side from in_sizes) ----------
__device__ __forceinline__ int get_edge(const void* p, int is64, long long idx) {
  if (is64) return (int)((const long long*)p)[idx];
  return ((const int*)p)[idx];
}

// ---------- CSR build over dst ----------
__global__ void degree_kernel(const void* eidx, int is64, int* deg) {
  int k = blockIdx.x * blockDim.x + threadIdx.x;
  if (k >= ET) return;
  int dst = (k < EE) ? get_edge(eidx, is64, (long long)EE + k) : (k - EE);
  atomicAdd(&deg[dst], 1);
}

__global__ __launch_bounds__(SCAN_BLK) void scan1_kernel(const int* __restrict__ deg,
                                                         int* __restrict__ rowptr,
                                                         int* __restrict__ bsum) {
  __shared__ int sm[SCAN_BLK];
  int t = threadIdx.x;
  int i = blockIdx.x * SCAN_BLK + t;
  int v = (i < NN) ? deg[i] : 0;
  sm[t] = v;
  __syncthreads();
#pragma unroll
  for (int o = 1; o < SCAN_BLK; o <<= 1) {
    int u = (t >= o) ? sm[t - o] : 0;
    __syncthreads();
    sm[t] += u;
    __syncthreads();
  }
  if (i < NN) rowptr[i] = sm[t] - v;                 // local exclusive
  if (t == SCAN_BLK - 1) bsum[blockIdx.x] = sm[t];   // block total
}

__global__ __launch_bounds__(128) void scan2_kernel(const int* __restrict__ bsum,
                                                    int* __restrict__ boff,
                                                    int* __restrict__ rowptr) {
  __shared__ int sm[128];
  int t = threadIdx.x;
  int v = (t < SCAN_NB) ? bsum[t] : 0;
  sm[t] = v;
  __syncthreads();
#pragma unroll
  for (int o = 1; o < 128; o <<= 1) {
    int u = (t >= o) ? sm[t - o] : 0;
    __syncthreads();
    sm[t] += u;
    __syncthreads();
  }
  if (t < SCAN_NB) boff[t] = sm[t] - v;  // exclusive block offset
  if (t == 0) rowptr[NN] = ET;
}

__global__ __launch_bounds__(SCAN_BLK) void scan3_kernel(int* __restrict__ rowptr,
                                                         int* __restrict__ cursor,
                                                         const int* __restrict__ boff) {
  int i = blockIdx.x * SCAN_BLK + threadIdx.x;
  if (i >= NN) return;
  int v = rowptr[i] + boff[blockIdx.x];
  rowptr[i] = v;
  cursor[i] = v;
}

__global__ void fill_kernel(const void* eidx, int is64, int* cursor, int* csr_src) {
  int k = blockIdx.x * blockDim.x + threadIdx.x;
  if (k >= ET) return;
  int src, dst;
  if (k < EE) {
    src = get_edge(eidx, is64, k);
    dst = get_edge(eidx, is64, (long long)EE + k);
  } else {
    src = dst = k - EE;
  }
  int pos = atomicAdd(&cursor[dst], 1);
  csr_src[pos] = src;
}

// all three weight transposes in one dispatch (grid.y selects the matrix)
__global__ void conv_w_kernel(const float* __restrict__ W0, const float* __restrict__ W1,
                              const float* __restrict__ W2,
                              ushort* __restrict__ T0, ushort* __restrict__ T1,
                              ushort* __restrict__ T2) {
  const float* W = (blockIdx.y == 0) ? W0 : (blockIdx.y == 1) ? W1 : W2;
  ushort* Wt = (blockIdx.y == 0) ? T0 : (blockIdx.y == 1) ? T1 : T2;
  int idx = blockIdx.x * 256 + threadIdx.x;  // 65536
  int k = idx >> 8, n = idx & 255;
  Wt[n * 256 + k] = f2bf(W[idx]);  // transpose: Wt[n][k]
}

// ---------- bf16 MFMA GEMM: 32x256 tile, A read ONCE (R3) ----------
// C[M,256] = A[M,256] @ B[256,256] (B given transposed).
// R3: grid.y=2 (64x128 tile) read A twice -> 32x256 tile reads A once,
// halving A-side HBM traffic (layer0 f32 51.2MB, layers1-2 aggb 25.6MB).
// Block = 32 rows x 256 cols, 4 waves, wave w = rows 0..31 x cols w*64..+64
// (2x4 16x16 subtiles, SAME 8-MFMA inner loop as before). 1563 blocks.
// LDS 20KB: As 2 subtiles (2KB), Bs 16 subtiles (16KB), stats 2KB.
// Wave w owns head w -> s/d epilogue unchanged in shape.
// MODE 1 prologue sums the 32-way GraphNorm partial buffers (fused in agg).
template <int MODE>
__global__ __launch_bounds__(256) void gemm_bf16(const void* __restrict__ Ap,
                                                 const ushort* __restrict__ Bt,
                                                 ushort* __restrict__ C,
                                                 const float* __restrict__ as_,
                                                 const float* __restrict__ ad_,
                                                 float* __restrict__ s_arr,
                                                 float* __restrict__ d_arr,
                                                 const float* __restrict__ statp,
                                                 const float* __restrict__ ga,
                                                 const float* __restrict__ gw,
                                                 const float* __restrict__ gb) {
  __shared__ ushort As[2 * 512];
  __shared__ ushort Bs[16 * 512];
  __shared__ float scs[FDIM], shs[FDIM];
  int tid = threadIdx.x, w = tid >> 6, l = tid & 63;
  int brow0 = blockIdx.x * 32;
  int lm = l & 15, lk = (l >> 4) * 8;
  // A staging: thread t covers 4 ushorts of subtile t>>7 at offset (t&127)*4.
  // Subtile layout (ushort off o): o = (k/8)*128 + row*8 + (k%8)  [proven layout]
  int s_sub = tid >> 7;
  int within = tid & 127;
  int arow = brow0 + s_sub * 16 + ((within >> 1) & 15);
  arow = min(arow, NN - 1);
  int kbase = ((within >> 5) << 3) + ((within & 1) << 2);
  size_t aoff = (size_t)arow * 256 + kbase;
  int aldst = s_sub * 512 + within * 4;
  // B staging: wave w stages subtiles 4w..4w+3 (the same ones it consumes)
  const ushort* bg[4];
#pragma unroll
  for (int j = 0; j < 4; j++)
    bg[j] = Bt + (size_t)((4 * w + j) * 16 + lm) * 256 + lk;

  if constexpr (MODE == 1) {
    // sum 32-way partial GraphNorm stats (written by agg's fused epilogue)
    float sa = 0.f, sb = 0.f, qa = 0.f, qb = 0.f;
    for (int k = 0; k < 32; k += 2) {
      sa += statp[k * 512 + tid];
      qa += statp[k * 512 + 256 + tid];
      sb += statp[(k + 1) * 512 + tid];
      qb += statp[(k + 1) * 512 + 256 + tid];
    }
    const float invn = 1.0f / (float)NN;
    float mu = (sa + sb) * invn;
    float ex2 = (qa + qb) * invn;
    float a = ga[tid];
    float var = fmaxf(ex2 - (2.f * a - a * a) * mu * mu, 0.f);
    float s = gw[tid] * rsqrtf(var + 1e-5f);
    scs[tid] = s;
    shs[tid] = gb[tid] - s * a * mu;
    __syncthreads();
  }

  floatx4 acc[2][4];
#pragma unroll
  for (int i = 0; i < 2; i++)
#pragma unroll
    for (int j = 0; j < 4; j++) acc[i][j] = floatx4{0.f, 0.f, 0.f, 0.f};

  for (int k0 = 0; k0 < 256; k0 += 32) {
    ushort4v av;
    if constexpr (MODE == 0) {
      float4 u = *(const float4*)((const float*)Ap + aoff + k0);
      av = ushort4v{f2bf(u.x), f2bf(u.y), f2bf(u.z), f2bf(u.w)};
    } else {
      ushort4v r = *(const ushort4v*)((const ushort*)Ap + aoff + k0);
      int kb = k0 + kbase;
#pragma unroll
      for (int j = 0; j < 4; j++) {
        float y = fmaf(scs[kb + j], bf2f(r[j]), shs[kb + j]);
        y = fmaxf(y, 0.01f * y);   // LeakyReLU(0.01)
        av[j] = f2bf(y);
      }
    }
    ushort8v b0 = *(const ushort8v*)(bg[0] + k0);
    ushort8v b1 = *(const ushort8v*)(bg[1] + k0);
    ushort8v b2 = *(const ushort8v*)(bg[2] + k0);
    ushort8v b3 = *(const ushort8v*)(bg[3] + k0);
    *(ushort4v*)&As[aldst] = av;
    *(ushort8v*)&Bs[(4 * w + 0) * 512 + l * 8] = b0;
    *(ushort8v*)&Bs[(4 * w + 1) * 512 + l * 8] = b1;
    *(ushort8v*)&Bs[(4 * w + 2) * 512 + l * 8] = b2;
    *(ushort8v*)&Bs[(4 * w + 3) * 512 + l * 8] = b3;
    __syncthreads();
    bf16x8 af[2], bfr[4];
    af[0] = *(const bf16x8*)&As[l * 8];
    af[1] = *(const bf16x8*)&As[512 + l * 8];
#pragma unroll
    for (int j = 0; j < 4; j++) bfr[j] = *(const bf16x8*)&Bs[(4 * w + j) * 512 + l * 8];
#pragma unroll
    for (int i = 0; i < 2; i++)
#pragma unroll
      for (int j = 0; j < 4; j++)
        acc[i][j] = __builtin_amdgcn_mfma_f32_16x16x32_bf16(af[i], bfr[j], acc[i][j], 0, 0, 0);
    __syncthreads();
  }

  int quad = l >> 4;
  // ----- C store -----
#pragma unroll
  for (int i = 0; i < 2; i++) {
    int rr0 = brow0 + i * 16 + quad * 4;
#pragma unroll
    for (int j = 0; j < 4; j++) {
      int col = w * 64 + j * 16 + lm;
#pragma unroll
      for (int r = 0; r < 4; r++) {
        int row = rr0 + r;
        if (row < NN) C[(size_t)row * 256 + col] = f2bf(acc[i][j][r]);
      }
    }
  }
  // ----- s/d epilogue: wave w owns head w for rows brow0..brow0+32 -----
  float asv[4], adv[4];
#pragma unroll
  for (int j = 0; j < 4; j++) {
    int col = w * 64 + j * 16 + lm;
    asv[j] = as_[col];
    adv[j] = ad_[col];
  }
#pragma unroll
  for (int i = 0; i < 2; i++) {
#pragma unroll
    for (int r = 0; r < 4; r++) {
      float sp = acc[i][0][r] * asv[0] + acc[i][1][r] * asv[1] +
                 acc[i][2][r] * asv[2] + acc[i][3][r] * asv[3];
      float dp = acc[i][0][r] * adv[0] + acc[i][1][r] * adv[1] +
                 acc[i][2][r] * adv[2] + acc[i][3][r] * adv[3];
      sp += __shfl_xor(sp, 1); dp += __shfl_xor(dp, 1);
      sp += __shfl_xor(sp, 2); dp += __shfl_xor(dp, 2);
      sp += __shfl_xor(sp, 4); dp += __shfl_xor(dp, 4);
      sp += __shfl_xor(sp, 8); dp += __shfl_xor(dp, 8);
      if (lm == 0) {
        int row = brow0 + i * 16 + quad * 4 + r;
        if (row < NN) {
          s_arr[row * HH + w] = sp;
          d_arr[row * HH + w] = dp;
        }
      }
    }
  }
}

// ---------- aggregation: one wave per node; 16-deep gather (R2, proven) ----------
// R3 adds: fused GraphNorm stat accumulation (f32, pre-rounding -> closer to ref)
// into 32-way partial buffers; kills the 3 norm_reduce dispatches and their
// full-buffer re-reads. Gather loop untouched (at L2-miss-path service floor).
template <bool CONCAT>
__global__ __launch_bounds__(256) void agg_kernel(const ushort* __restrict__ hb,
                                                  const float* __restrict__ s_arr,
                                                  const float* __restrict__ d_arr,
                                                  const int* __restrict__ rowptr,
                                                  const int* __restrict__ csr_src,
                                                  const float* __restrict__ bias,
                                                  void* __restrict__ outp,
                                                  float* __restrict__ statp) {
  __shared__ float4 ssm[4][64];
  __shared__ float4 sqm[4][64];
  int w = __builtin_amdgcn_readfirstlane(threadIdx.x >> 6);
  int l = threadIdx.x & 63;
  int head = l >> 4;
  int n = blockIdx.x * 4 + w;
  int beg = rowptr[n], end = rowptr[n + 1];
  float dh = d_arr[n * HH + head];
  float a0 = 0.f, a1 = 0.f, a2 = 0.f, a3 = 0.f, den = 0.f;

  int i = beg;
  // ---- 16-deep main: all loads issued before any consume (max MLP) ----
  for (; i + 16 <= end; i += 16) {
    int ss[16];
#pragma unroll
    for (int t = 0; t < 16; t++) ss[t] = csr_src[i + t];
    float ee[16];
#pragma unroll
    for (int t = 0; t < 16; t++) ee[t] = s_arr[ss[t] * HH + head];
    ushort4s hh[16];
#pragma unroll
    for (int t = 0; t < 16; t++)
      hh[t] = *(const ushort4s*)(hb + (unsigned)(ss[t] * FDIM + l * 4));
#pragma unroll
    for (int t = 0; t < 16; t++) {
      float e = ee[t] + dh;
      e = (e > 0.f) ? e : 0.2f * e;
      float wt = __expf(e);
      den += wt;
      a0 = fmaf(wt, bf2f(hh[t].x), a0);
      a1 = fmaf(wt, bf2f(hh[t].y), a1);
      a2 = fmaf(wt, bf2f(hh[t].z), a2);
      a3 = fmaf(wt, bf2f(hh[t].w), a3);
    }
  }
  // ---- 8-tier ----
  for (; i + 8 <= end; i += 8) {
    int ss[8];
#pragma unroll
    for (int t = 0; t < 8; t++) ss[t] = csr_src[i + t];
    float ee[8];
#pragma unroll
    for (int t = 0; t < 8; t++) ee[t] = s_arr[ss[t] * HH + head];
    ushort4s hh[8];
#pragma unroll
    for (int t = 0; t < 8; t++)
      hh[t] = *(const ushort4s*)(hb + (unsigned)(ss[t] * FDIM + l * 4));
#pragma unroll
    for (int t = 0; t < 8; t++) {
      float e = ee[t] + dh;
      e = (e > 0.f) ? e : 0.2f * e;
      float wt = __expf(e);
      den += wt;
      a0 = fmaf(wt, bf2f(hh[t].x), a0);
      a1 = fmaf(wt, bf2f(hh[t].y), a1);
      a2 = fmaf(wt, bf2f(hh[t].z), a2);
      a3 = fmaf(wt, bf2f(hh[t].w), a3);
    }
  }
  // ---- 4-tier ----
  for (; i + 4 <= end; i += 4) {
    int ss[4];
#pragma unroll
    for (int t = 0; t < 4; t++) ss[t] = csr_src[i + t];
    float ee[4];
#pragma unroll
    for (int t = 0; t < 4; t++) ee[t] = s_arr[ss[t] * HH + head];
    ushort4s hh[4];
#pragma unroll
    for (int t = 0; t < 4; t++)
      hh[t] = *(const ushort4s*)(hb + (unsigned)(ss[t] * FDIM + l * 4));
#pragma unroll
    for (int t = 0; t < 4; t++) {
      float e = ee[t] + dh;
      e = (e > 0.f) ? e : 0.2f * e;
      float wt = __expf(e);
      den += wt;
      a0 = fmaf(wt, bf2f(hh[t].x), a0);
      a1 = fmaf(wt, bf2f(hh[t].y), a1);
      a2 = fmaf(wt, bf2f(hh[t].z), a2);
      a3 = fmaf(wt, bf2f(hh[t].w), a3);
    }
  }
  // ---- scalar tail ----
  for (; i < end; i++) {
    int s0 = csr_src[i];
    float e0 = s_arr[s0 * HH + head] + dh;
    ushort4s h0 = *(const ushort4s*)(hb + (unsigned)(s0 * FDIM + l * 4));
    e0 = (e0 > 0.f) ? e0 : 0.2f * e0;
    float w0 = __expf(e0);
    den += w0;
    a0 = fmaf(w0, bf2f(h0.x), a0); a1 = fmaf(w0, bf2f(h0.y), a1);
    a2 = fmaf(w0, bf2f(h0.z), a2); a3 = fmaf(w0, bf2f(h0.w), a3);
  }
  float inv = 1.0f / den;  // self loop guarantees den > 0
  float r0 = a0 * inv, r1 = a1 * inv, r2 = a2 * inv, r3 = a3 * inv;

  if (CONCAT) {
    float4 bv = ((const float4*)bias)[l];
    float ox = r0 + bv.x, oy = r1 + bv.y, oz = r2 + bv.z, ow = r3 + bv.w;
    ushort4s o;
    o.x = f2bf(ox); o.y = f2bf(oy); o.z = f2bf(oz); o.w = f2bf(ow);
    ((ushort4s*)outp)[(unsigned)(n * 64 + l)] = o;
    ssm[w][l] = float4{ox, oy, oz, ow};
    sqm[w][l] = float4{ox * ox, oy * oy, oz * oz, ow * ow};
    __syncthreads();
    int tid = threadIdx.x;
    if (tid < 64) {
      float4 A = ssm[0][tid], B = ssm[1][tid], Cc = ssm[2][tid], D = ssm[3][tid];
      float* p = statp + (blockIdx.x & 31) * 512 + tid * 4;
      atomicAdd(p + 0, A.x + B.x + Cc.x + D.x);
      atomicAdd(p + 1, A.y + B.y + Cc.y + D.y);
      atomicAdd(p + 2, A.z + B.z + Cc.z + D.z);
      atomicAdd(p + 3, A.w + B.w + Cc.w + D.w);
      float4 E = sqm[0][tid], F = sqm[1][tid], G = sqm[2][tid], Hq = sqm[3][tid];
      float* q = p + 256;
      atomicAdd(q + 0, E.x + F.x + G.x + Hq.x);
      atomicAdd(q + 1, E.y + F.y + G.y + Hq.y);
      atomicAdd(q + 2, E.z + F.z + G.z + Hq.z);
      atomicAdd(q + 3, E.w + F.w + G.w + Hq.w);
    }
  } else {
    r0 += __shfl_xor(r0, 16); r1 += __shfl_xor(r1, 16);
    r2 += __shfl_xor(r2, 16); r3 += __shfl_xor(r3, 16);
    r0 += __shfl_xor(r0, 32); r1 += __shfl_xor(r1, 32);
    r2 += __shfl_xor(r2, 32); r3 += __shfl_xor(r3, 32);
    if (l < 16) {
      float4 bv = ((const float4*)bias)[l];
      float4 o;
      o.x = 0.25f * r0 + bv.x; o.y = 0.25f * r1 + bv.y;
      o.z = 0.25f * r2 + bv.z; o.w = 0.25f * r3 + bv.w;
      ((float4*)outp)[(unsigned)(n * 16 + l)] = o;
      ssm[w][l] = o;
      sqm[w][l] = float4{o.x * o.x, o.y * o.y, o.z * o.z, o.w * o.w};
    }
    __syncthreads();
    int tid = threadIdx.x;
    if (tid < 16) {
      float4 A = ssm[0][tid], B = ssm[1][tid], Cc = ssm[2][tid], D = ssm[3][tid];
      float* p = statp + (blockIdx.x & 31) * 128 + tid * 4;
      atomicAdd(p + 0, A.x + B.x + Cc.x + D.x);
      atomicAdd(p + 1, A.y + B.y + Cc.y + D.y);
      atomicAdd(p + 2, A.z + B.z + Cc.z + D.z);
      atomicAdd(p + 3, A.w + B.w + Cc.w + D.w);
      float4 E = sqm[0][tid], F = sqm[1][tid], G = sqm[2][tid], Hq = sqm[3][tid];
      float* q = p + 64;
      atomicAdd(q + 0, E.x + F.x + G.x + Hq.x);
      atomicAdd(q + 1, E.y + F.y + G.y + Hq.y);
      atomicAdd(q + 2, E.z + F.z + G.z + Hq.z);
      atomicAdd(q + 3, E.w + F.w + G.w + Hq.w);
    }
  }
}

// ---------- MLP 64->32->16->2 with fused GraphNorm+LeakyReLU on input ----------
__global__ __launch_bounds__(256) void mlp_kernel(const float* __restrict__ xin,
                                                  const float* __restrict__ statp,
                                                  const float* __restrict__ ga,
                                                  const float* __restrict__ gw,
                                                  const float* __restrict__ gb,
                                                  const float* mW0, const float* mb0,
                                                  const float* mW1, const float* mb1,
                                                  const float* mW2, const float* mb2,
                                                  float* __restrict__ out) {
  __shared__ float W0s[64 * 32];
  __shared__ float W1s[32 * 16];
  __shared__ float W2s[16 * 2];
  __shared__ float b0s[32], b1s[16], b2s[2];
  __shared__ float sc[CC], sh[CC];
  int t = threadIdx.x;
  for (int i = t; i < 2048; i += 256) W0s[i] = mW0[i];
  for (int i = t; i < 512; i += 256) W1s[i] = mW1[i];
  if (t < 32) { W2s[t] = mW2[t]; b0s[t] = mb0[t]; }
  if (t < 16) b1s[t] = mb1[t];
  if (t < 2) b2s[t] = mb2[t];
  if (t < CC) {
    float s_ = 0.f, q_ = 0.f;
    for (int k = 0; k < 32; k++) {
      s_ += statp[k * 128 + t];
      q_ += statp[k * 128 + 64 + t];
    }
    const float invn = 1.0f / (float)NN;
    float mu = s_ * invn;
    float ex2 = q_ * invn;
    float a = ga[t];
    float var = fmaxf(ex2 - (2.f * a - a * a) * mu * mu, 0.f);
    float s = gw[t] * rsqrtf(var + 1e-5f);
    sc[t] = s; sh[t] = gb[t] - s * a * mu;
  }
  __syncthreads();
  int node = blockIdx.x * 256 + t;
  if (node >= NN) return;
  float in[64];
  const float* xr = xin + (size_t)node * 64;
#pragma unroll
  for (int k = 0; k < 64; k++) {
    float y = sc[k] * xr[k] + sh[k];
    in[k] = (y > 0.f) ? y : 0.01f * y;   // GraphNorm + LeakyReLU(0.01) fused
  }
  float h1[32];
#pragma unroll
  for (int j = 0; j < 32; j++) h1[j] = b0s[j];
#pragma unroll
  for (int k = 0; k < 64; k++) {
    float v = in[k];
#pragma unroll
    for (int j = 0; j < 32; j++) h1[j] += v * W0s[k * 32 + j];
  }
#pragma unroll
  for (int j = 0; j < 32; j++) h1[j] = fmaxf(h1[j], 0.f);
  float h2[16];
#pragma unroll
  for (int j = 0; j < 16; j++) h2[j] = b1s[j];
#pragma unroll
  for (int k = 0; k < 32; k++) {
    float v = h1[k];
#pragma unroll
    for (int j = 0; j < 16; j++) h2[j] += v * W1s[k * 16 + j];
  }
#pragma unroll
  for (int j = 0; j < 16; j++) h2[j] = fmaxf(h2[j], 0.f);
  float o0 = b2s[0], o1 = b2s[1];
#pragma unroll
  for (int k = 0; k < 16; k++) {
    o0 += h2[k] * W2s[k * 2 + 0];
    o1 += h2[k] * W2s[k * 2 + 1];
  }
  out[(size_t)node * 2 + 0] = o0;
  out[(size_t)node * 2 + 1] = o1;
}

extern "C" void kernel_launch(void* const* d_in, const int* in_sizes, int n_in,
                              void* d_out, int out_size, void* d_ws, size_t ws_size,
                              hipStream_t stream) {
  const float* x = (const float*)d_in[0];
  const void* ei = d_in[1];
  const float* W[3]   = {(const float*)d_in[2],  (const float*)d_in[9],  (const float*)d_in[16]};
  const float* as_[3] = {(const float*)d_in[3],  (const float*)d_in[10], (const float*)d_in[17]};
  const float* ad_[3] = {(const float*)d_in[4],  (const float*)d_in[11], (const float*)d_in[18]};
  const float* b_[3]  = {(const float*)d_in[5],  (const float*)d_in[12], (const float*)d_in[19]};
  const float* gw[3]  = {(const float*)d_in[6],  (const float*)d_in[13], (const float*)d_in[20]};
  const float* gb[3]  = {(const float*)d_in[7],  (const float*)d_in[14], (const float*)d_in[21]};
  const float* ga[3]  = {(const float*)d_in[8],  (const float*)d_in[15], (const float*)d_in[22]};
  const float* mW0 = (const float*)d_in[23];
  const float* mb0 = (const float*)d_in[24];
  const float* mW1 = (const float*)d_in[25];
  const float* mb1 = (const float*)d_in[26];
  const float* mW2 = (const float*)d_in[27];
  const float* mb2 = (const float*)d_in[28];
  float* out = (float*)d_out;

  // edge-index dtype from byte size: int64 => 2*EE*8 bytes
  int is64 = (in_sizes[1] == (int)(2u * EE * 8u)) ? 1 : 0;

  char* ws = (char*)d_ws;
  size_t off = 0;
  auto take = [&](size_t bytes) -> char* {
    char* p = ws + off;
    off = (off + bytes + 255) & ~(size_t)255;
    return p;
  };
  ushort* hb    = (ushort*)take((size_t)NN * FDIM * 2);
  ushort* aggb  = (ushort*)take((size_t)NN * FDIM * 2);
  float* bufD   = (float*)take((size_t)NN * CC * 4);
  ushort* Wt[3];
  for (int i = 0; i < 3; i++) Wt[i] = (ushort*)take((size_t)256 * 256 * 2);
  float* s_arr  = (float*)take((size_t)NN * HH * 4);
  float* d_arr  = (float*)take((size_t)NN * HH * 4);
  // zero-region: deg + 32-way partial stat buffers -> ONE memset
  char* zbase   = (char*)take(0);
  int* deg      = (int*)take((size_t)NN * 4);
  float* cs01[2];
  for (int i = 0; i < 2; i++) cs01[i] = (float*)take(32 * 512 * 4);  // layers 0,1: [32][512]
  float* cs2    = (float*)take(32 * 128 * 4);                        // layer 2:   [32][128]
  size_t zlen   = (size_t)(((char*)cs2 + 32 * 128 * 4) - zbase);
  int* cursor   = (int*)take((size_t)NN * 4);
  int* rowptr   = (int*)take((size_t)(NN + 1) * 4);
  int* csr_src  = (int*)take((size_t)ET * 4);
  int* bsum     = (int*)take(512);
  int* boff     = (int*)take(512);

  hipMemsetAsync(zbase, 0, zlen, stream);   // deg + all partial norm stats

  // CSR build (reused by all 3 layers)
  degree_kernel<<<(ET + 255) / 256, 256, 0, stream>>>(ei, is64, deg);
  scan1_kernel<<<SCAN_NB, SCAN_BLK, 0, stream>>>(deg, rowptr, bsum);
  scan2_kernel<<<1, 128, 0, stream>>>(bsum, boff, rowptr);
  scan3_kernel<<<SCAN_NB, SCAN_BLK, 0, stream>>>(rowptr, cursor, boff);
  fill_kernel<<<(ET + 255) / 256, 256, 0, stream>>>(ei, is64, cursor, csr_src);

  // weight prep (x is consumed in f32 directly by layer-0 gemm)
  conv_w_kernel<<<dim3(256, 3), 256, 0, stream>>>(W[0], W[1], W[2], Wt[0], Wt[1], Wt[2]);

  int ggrid = (NN + 31) / 32;   // 1563
  for (int L = 0; L < 3; L++) {
    if (L == 0)
      gemm_bf16<0><<<ggrid, 256, 0, stream>>>((const void*)x, Wt[0], hb,
                                              as_[0], ad_[0], s_arr, d_arr,
                                              nullptr, nullptr, nullptr, nullptr);
    else
      gemm_bf16<1><<<ggrid, 256, 0, stream>>>((const void*)aggb, Wt[L], hb,
                                              as_[L], ad_[L], s_arr, d_arr,
                                              cs01[L - 1], ga[L - 1], gw[L - 1], gb[L - 1]);
    if (L < 2) {
      agg_kernel<true><<<NN / 4, 256, 0, stream>>>(hb, s_arr, d_arr, rowptr, csr_src,
                                                   b_[L], aggb, cs01[L]);
    } else {
      agg_kernel<false><<<NN / 4, 256, 0, stream>>>(hb, s_arr, d_arr, rowptr, csr_src,
                                                    b_[L], bufD, cs2);
    }
  }
  mlp_kernel<<<(NN + 255) / 256, 256, 0, stream>>>(bufD, cs2,
                                                   ga[2], gw[2], gb[2],
                                                   mW0, mb0, mW1, mb1, mW2, mb2, out);
}